// Round 10
// baseline (26.104 us; speedup 1.0000x reference)
//
#include <hip/hip_runtime.h>

#define NCLS 64
#define TDIM 512
#define PD   8   // prefetch depth (general path)

typedef _Float16 h2 __attribute__((ext_vector_type(2)));

#if __has_builtin(__builtin_amdgcn_fdot2)
#define FDOT2(a, b, c) __builtin_amdgcn_fdot2((a), (b), (c), false)
#else
static __device__ __forceinline__ float FDOT2(h2 a, h2 b, float c) {
    return fmaf((float)a.x, (float)b.x, fmaf((float)a.y, (float)b.y, c));
}
#endif

#define BC_H2(x) __builtin_bit_cast(h2, (x))
#define LN64 4.1588830833596715f

// Uniform-T fast math (exact factorization):
//   L_t = LSE_i(lg_t,i/64) independent per t,
//   partition(len) = R_{len-1} + 64*(len*c + ln64 + sum_{u<=len-2} L_u)
//   gold = lg[0,tg0] + 64c + len*c + sum_{m=1..len} lg[m, tg_m]
// Per-row contribution (everything sample-row-local):
static __device__ __forceinline__ float row_contrib(
    const float* __restrict__ lg, const int* __restrict__ tg, int row, int len)
{
    const float I64 = 1.0f / 64.0f;
    float contrib = 0.f;
    if (row < len) {
        const float4* rp = reinterpret_cast<const float4*>(lg + (size_t)row * NCLS);
        float4 vv[16];
        #pragma unroll
        for (int q = 0; q < 16; ++q) vv[q] = rp[q];   // 16 independent loads
        float mx = -3.0e38f;
        #pragma unroll
        for (int q = 0; q < 16; ++q)
            mx = fmaxf(mx, fmaxf(fmaxf(vv[q].x, vv[q].y), fmaxf(vv[q].z, vv[q].w)));
        float es = 0.f;
        #pragma unroll
        for (int q = 0; q < 16; ++q)
            es += __expf((vv[q].x - mx) * I64) + __expf((vv[q].y - mx) * I64)
                + __expf((vv[q].z - mx) * I64) + __expf((vv[q].w - mx) * I64);
        if (row <= len - 2)
            contrib += 64.0f * (mx * I64 + __logf(es));        // 64 * L_row
        if (row == len - 1) {
            float rs = 0.f;
            #pragma unroll
            for (int q = 0; q < 16; ++q) rs += (vv[q].x + vv[q].y) + (vv[q].z + vv[q].w);
            contrib += rs * I64;                               // R_{len-1}
        }
    }
    if (row >= 1 && row <= len) contrib -= lg[(size_t)row * NCLS + tg[row]];
    return contrib;
}

// Kernel 1: block (n,c) = sample n, row chunk [64c, 64c+64). One wave per block.
// Writes partial sums to ws[n*8+c]; uniformity flag to ws[N*8] (block 0,0).
// If T is non-uniform, block (n,0) runs the general serial recurrence and
// writes the COMPLETE result to ws[n*8] (kernel 2 passes it through).
__global__ __launch_bounds__(64) void crf_part(
    const float* __restrict__ logits,   // [N, T, C] f32
    const int*   __restrict__ lengths,  // [N] i32
    const int*   __restrict__ tags,     // [N, T] i32
    const float* __restrict__ trans,    // [C, C] f32
    float* __restrict__ ws, int N)
{
    const int bid = blockIdx.x;
    const int n   = bid >> 3;
    const int c   = bid & 7;
    if (n >= N) return;
    const int lane = threadIdx.x;       // 0..63

    const int len = lengths[n];               // in [1, T-1]
    const float* lg = logits + (size_t)n * TDIM * NCLS;
    const int*   tg = tags   + (size_t)n * TDIM;

    if (c != 0) {
        // Uniform-path partial, computed unconditionally (ignored if general).
        float contrib = row_contrib(lg, tg, c * 64 + lane, len);
        #pragma unroll
        for (int o = 32; o; o >>= 1) contrib += __shfl_xor(contrib, o);
        if (lane == 0) ws[n * 8 + c] = contrib;
        return;
    }

    // ---- c == 0: full uniformity check (64 lanes x own trans row) ----
    const unsigned c0b = __builtin_bit_cast(unsigned, trans[0]);
    float4 tvv[16];
    #pragma unroll
    for (int q = 0; q < 16; ++q)
        tvv[q] = *reinterpret_cast<const float4*>(&trans[lane * NCLS + q * 4]);
    int eq = 1;
    #pragma unroll
    for (int q = 0; q < 16; ++q) {
        eq &= (__builtin_bit_cast(unsigned, tvv[q].x) == c0b);
        eq &= (__builtin_bit_cast(unsigned, tvv[q].y) == c0b);
        eq &= (__builtin_bit_cast(unsigned, tvv[q].z) == c0b);
        eq &= (__builtin_bit_cast(unsigned, tvv[q].w) == c0b);
    }
    const bool uni = (__ballot(eq) == ~0ULL);
    if (n == 0 && lane == 0) ws[8 * N] = uni ? 1.0f : 0.0f;

    if (uni) {
        float contrib = row_contrib(lg, tg, lane, len);
        if (lane == 0) contrib -= lg[tg[0]];
        #pragma unroll
        for (int o = 32; o; o >>= 1) contrib += __shfl_xor(contrib, o);
        if (lane == 0) ws[n * 8] = contrib;
        return;
    }

    // =============== GENERAL PATH (this wave only) ===============
    __shared__ __align__(16) _Float16 fh_lds[NCLS];
    const float INV_C = 1.0f / (float)NCLS;

    int tr8[PD];
    #pragma unroll
    for (int k = 0; k < PD; ++k) tr8[k] = tg[lane + NCLS * k];

    float trow[NCLS];
    #pragma unroll
    for (int q = 0; q < 16; ++q) {
        trow[4*q] = tvv[q].x; trow[4*q+1] = tvv[q].y;
        trow[4*q+2] = tvv[q].z; trow[4*q+3] = tvv[q].w;
    }
    float tmax = -3.0e38f, tsum = 0.f;
    #pragma unroll
    for (int j = 0; j < NCLS; ++j) { tmax = fmaxf(tmax, trow[j]); tsum += trow[j]; }
    float mT = tmax;
    #pragma unroll
    for (int o = 32; o; o >>= 1) mT = fmaxf(mT, __shfl_xor(mT, o));
    h2 tp[NCLS / 2];
    #pragma unroll
    for (int j = 0; j < NCLS; j += 2) {
        const float e0 = __expf(trow[j]     - mT) * 0.015625f;
        const float e1 = __expf(trow[j + 1] - mT) * 0.015625f;
        h2 p; p.x = (_Float16)e0; p.y = (_Float16)e1;
        tp[j >> 1] = p;
    }

    const int   t0 = __shfl(tr8[0], 0);          // tags[0]
    const float rs = __shfl(tsum, t0);           // row-sum of T at row tags[0]
    const float first = lg[t0] + rs;

    float f = 1.0f;
    float B = 0.0f;

    float lgr[PD];
    #pragma unroll
    for (int k = 0; k < PD; ++k) lgr[k] = lg[(size_t)k * NCLS + lane];

    const int nblk = len >> 3;
    const int tail = len & 7;

    #define CRF_STEP(PVAL)                                                     \
    {                                                                          \
        fh_lds[lane] = (_Float16)f;                                            \
        float d0 = 0.f, d1 = 0.f, d2 = 0.f, d3 = 0.f;                          \
        _Pragma("unroll")                                                      \
        for (int j = 0; j < NCLS; j += 16) {                                   \
            const float4 a  = *reinterpret_cast<const float4*>(&fh_lds[j]);    \
            const float4 b4 = *reinterpret_cast<const float4*>(&fh_lds[j+8]);  \
            d0 = FDOT2(tp[(j >> 1) + 0], BC_H2(a.x),  d0);                     \
            d1 = FDOT2(tp[(j >> 1) + 1], BC_H2(a.y),  d1);                     \
            d2 = FDOT2(tp[(j >> 1) + 2], BC_H2(a.z),  d2);                     \
            d3 = FDOT2(tp[(j >> 1) + 3], BC_H2(a.w),  d3);                     \
            d0 = FDOT2(tp[(j >> 1) + 4], BC_H2(b4.x), d0);                     \
            d1 = FDOT2(tp[(j >> 1) + 5], BC_H2(b4.y), d1);                     \
            d2 = FDOT2(tp[(j >> 1) + 6], BC_H2(b4.z), d2);                     \
            d3 = FDOT2(tp[(j >> 1) + 7], BC_H2(b4.w), d3);                     \
        }                                                                      \
        const float dot = (d0 + d1) + (d2 + d3);                               \
        f = dot * (PVAL);                                                      \
    }

    int t = 0;
    for (int b = 0; b < nblk; ++b) {
        #pragma unroll
        for (int k = 0; k < PD; ++k) {
            const float p = __expf(lgr[k] * INV_C);      // off critical path
            int nidx = t + k + PD; nidx = (nidx > TDIM - 1) ? (TDIM - 1) : nidx;
            lgr[k] = lg[(size_t)nidx * NCLS + lane];     // lands 8 steps out
            CRF_STEP(p);
        }
        t += PD;
        if ((b & 7) == 7) {            // periodic renorm
            float r = __builtin_bit_cast(float,
                          __builtin_amdgcn_readfirstlane(__builtin_bit_cast(int, f)));
            r = fmaxf(r, 1e-30f);
            f *= __builtin_amdgcn_rcpf(r);
            B += __logf(r);
        }
    }

    #pragma unroll
    for (int k = 0; k < PD - 1; ++k) {
        if (k < tail) {
            const float p = __expf(lgr[k] * INV_C);
            CRF_STEP(p);
        }
    }
    #undef CRF_STEP

    float g = 0.f;
    #pragma unroll
    for (int k = 0; k < PD; ++k) {
        const int m = 1 + lane + NCLS * k;
        if (m <= len) {
            const int rot  = __shfl(tr8[k], (lane + 1) & 63);        // tg[m], lane<63
            const int wrap = __shfl(tr8[(k + 1) & (PD - 1)], 0);     // tg[m], lane==63
            const int tm = (lane == 63) ? wrap : rot;
            const int tp_ = tr8[k];                                   // tg[m-1]
            g += trans[tm * NCLS + tp_] + lg[(size_t)m * NCLS + tm];
        }
    }

    float v = __logf(f) - g;
    #pragma unroll
    for (int o = 32; o; o >>= 1) v += __shfl_xor(v, o);

    if (lane == 0) {
        const float Bt = (float)len * (mT + LN64) + B;
        ws[n * 8] = 64.0f * Bt + v - first;       // complete result
    }
}

// Kernel 2: fold 8 partials + analytic constant into out[n].
__global__ __launch_bounds__(64) void crf_fin(
    const int*   __restrict__ lengths,
    const float* __restrict__ trans,
    const float* __restrict__ ws,
    float* __restrict__ out, int N)
{
    const int n = blockIdx.x * 64 + threadIdx.x;
    if (n >= N) return;
    const float flag = ws[8 * N];
    if (flag != 0.0f) {
        float s = 0.f;
        #pragma unroll
        for (int c = 0; c < 8; ++c) s += ws[n * 8 + c];
        const int   len = lengths[n];
        const float cc  = trans[0];
        out[n] = s + 64.0f * ((float)len * cc + LN64) - 64.0f * cc - (float)len * cc;
    } else {
        out[n] = ws[n * 8];    // general path wrote the complete result
    }
}

extern "C" void kernel_launch(void* const* d_in, const int* in_sizes, int n_in,
                              void* d_out, int out_size, void* d_ws, size_t ws_size,
                              hipStream_t stream) {
    const float* logits  = (const float*)d_in[0];
    const int*   lengths = (const int*)  d_in[1];
    const int*   tags    = (const int*)  d_in[2];
    const float* trans   = (const float*)d_in[3];
    float* out = (float*)d_out;
    float* ws  = (float*)d_ws;          // needs (N*8 + 1) floats = 16.4 KB
    const int N = in_sizes[1];          // 512

    crf_part<<<N * 8, 64, 0, stream>>>(logits, lengths, tags, trans, ws, N);
    crf_fin <<<(N + 63) / 64, 64, 0, stream>>>(lengths, trans, ws, out, N);
}

// Round 11
// 21.886 us; speedup vs baseline: 1.1927x; 1.1927x over previous
//
#include <hip/hip_runtime.h>

#define NCLS 64
#define TDIM 512
#define PD   8   // prefetch depth (general path)

typedef _Float16 h2 __attribute__((ext_vector_type(2)));

#if __has_builtin(__builtin_amdgcn_fdot2)
#define FDOT2(a, b, c) __builtin_amdgcn_fdot2((a), (b), (c), false)
#else
static __device__ __forceinline__ float FDOT2(h2 a, h2 b, float c) {
    return fmaf((float)a.x, (float)b.x, fmaf((float)a.y, (float)b.y, c));
}
#endif

#define BC_H2(x) __builtin_bit_cast(h2, (x))
#define LN64 4.1588830833596715f

#define CROWS 128          // rows staged per chunk
#define F4PAD 17           // float4 row stride in LDS (16 + 1 pad)

// Single kernel. Uniform-T fast path (exact factorization):
//   L_t = LSE_i(lg_t,i/64) independent per t,
//   partition(len) = R_{len-1} + 64*(len*c + ln64 + sum_{u<=len-2} L_u)
//   gold = lg[0,tg0] + 64c + len*c + sum_{m=1..len} lg[m, tg_m]
// Fast path: chunks of 128 rows are staged into LDS with fully-coalesced
// float4 loads (lane i <-> addr 16i), then consumed 4-threads-per-row with
// depth-2 shuffle combines. General path: round-4 serial recurrence (wave 0).
__global__ __launch_bounds__(512) void crf_kernel(
    const float* __restrict__ logits,   // [N, T, C] f32
    const int*   __restrict__ lengths,  // [N] i32
    const int*   __restrict__ tags,     // [N, T] i32
    const float* __restrict__ trans,    // [C, C] f32
    float* __restrict__ out, int N)
{
    const int n = blockIdx.x;
    if (n >= N) return;
    const int tid = threadIdx.x;

    __shared__ __align__(16) float s_stage[CROWS * F4PAD * 4];  // 34.8 KB
    __shared__ float sRed[8];
    __shared__ __align__(16) _Float16 fh_lds[NCLS];

    // ---- uniformity vote: 4096 words, 8 per thread, one HW-vote barrier ----
    int ok;
    {
        const unsigned c0b = __builtin_bit_cast(unsigned, trans[0]);
        const float4 a = reinterpret_cast<const float4*>(trans)[tid * 2];
        const float4 b = reinterpret_cast<const float4*>(trans)[tid * 2 + 1];
        ok  = (__builtin_bit_cast(unsigned, a.x) == c0b);
        ok &= (__builtin_bit_cast(unsigned, a.y) == c0b);
        ok &= (__builtin_bit_cast(unsigned, a.z) == c0b);
        ok &= (__builtin_bit_cast(unsigned, a.w) == c0b);
        ok &= (__builtin_bit_cast(unsigned, b.x) == c0b);
        ok &= (__builtin_bit_cast(unsigned, b.y) == c0b);
        ok &= (__builtin_bit_cast(unsigned, b.z) == c0b);
        ok &= (__builtin_bit_cast(unsigned, b.w) == c0b);
    }
    const int uni = __syncthreads_and(ok);

    const int len = lengths[n];               // in [1, T-1]
    const float* lg = logits + (size_t)n * TDIM * NCLS;
    const int*   tg = tags   + (size_t)n * TDIM;
    const float I64 = 1.0f / 64.0f;

    if (uni) {
        // =============== FAST PATH ===============
        float contrib = 0.f;

        // gold gathers first: scattered 4B loads overlap the staging below
        if (tid >= 1 && tid <= len) contrib -= lg[(size_t)tid * NCLS + tg[tid]];
        if (tid == 0)               contrib -= lg[tg[0]];

        const int nch = (len + CROWS - 1) >> 7;          // 1..4, block-uniform
        const float4* gf4 = reinterpret_cast<const float4*>(lg);
        float4* sf4 = reinterpret_cast<float4*>(s_stage);

        const int r_ = tid >> 2;        // row within chunk (0..127)
        const int p_ = tid & 3;         // quarter within row

        for (int ch = 0; ch < nch; ++ch) {
            // ---- stage 128 rows (2048 float4) coalesced ----
            #pragma unroll
            for (int i = 0; i < 4; ++i) {
                const int q = tid + 512 * i;             // 0..2047
                const float4 v = gf4[(ch << 11) + q];
                sf4[(q >> 4) * F4PAD + (q & 15)] = v;
            }
            __syncthreads();

            // ---- consume: 4 threads per row, 16 floats each ----
            const int row = (ch << 7) + r_;
            float4 w0 = sf4[r_ * F4PAD + p_ * 4 + 0];
            float4 w1 = sf4[r_ * F4PAD + p_ * 4 + 1];
            float4 w2 = sf4[r_ * F4PAD + p_ * 4 + 2];
            float4 w3 = sf4[r_ * F4PAD + p_ * 4 + 3];

            float mx = fmaxf(fmaxf(fmaxf(w0.x, w0.y), fmaxf(w0.z, w0.w)),
                             fmaxf(fmaxf(w1.x, w1.y), fmaxf(w1.z, w1.w)));
            mx = fmaxf(mx, fmaxf(fmaxf(fmaxf(w2.x, w2.y), fmaxf(w2.z, w2.w)),
                                 fmaxf(fmaxf(w3.x, w3.y), fmaxf(w3.z, w3.w))));
            mx = fmaxf(mx, __shfl_xor(mx, 1));
            mx = fmaxf(mx, __shfl_xor(mx, 2));           // row max (depth 2)

            float es = __expf((w0.x - mx) * I64) + __expf((w0.y - mx) * I64)
                     + __expf((w0.z - mx) * I64) + __expf((w0.w - mx) * I64)
                     + __expf((w1.x - mx) * I64) + __expf((w1.y - mx) * I64)
                     + __expf((w1.z - mx) * I64) + __expf((w1.w - mx) * I64)
                     + __expf((w2.x - mx) * I64) + __expf((w2.y - mx) * I64)
                     + __expf((w2.z - mx) * I64) + __expf((w2.w - mx) * I64)
                     + __expf((w3.x - mx) * I64) + __expf((w3.y - mx) * I64)
                     + __expf((w3.z - mx) * I64) + __expf((w3.w - mx) * I64);
            es += __shfl_xor(es, 1);
            es += __shfl_xor(es, 2);                     // row expsum (depth 2)

            if (p_ == 0 && row <= len - 2)
                contrib += 64.0f * (mx * I64 + __logf(es));   // 64 * L_row

            if (row == len - 1) {                        // R_{len-1} (one row)
                float rs = (w0.x + w0.y) + (w0.z + w0.w)
                         + (w1.x + w1.y) + (w1.z + w1.w)
                         + (w2.x + w2.y) + (w2.z + w2.w)
                         + (w3.x + w3.y) + (w3.z + w3.w);
                rs += __shfl_xor(rs, 1);
                rs += __shfl_xor(rs, 2);
                if (p_ == 0) contrib += rs * I64;
            }
            __syncthreads();          // LDS consumed; safe to restage
        }

        // ---- one block-wide reduction ----
        #pragma unroll
        for (int o = 32; o; o >>= 1) contrib += __shfl_xor(contrib, o);
        if ((tid & 63) == 0) sRed[tid >> 6] = contrib;
        __syncthreads();
        if (tid == 0) {
            float s = 0.f;
            #pragma unroll
            for (int w = 0; w < 8; ++w) s += sRed[w];
            const float c = trans[0];
            out[n] = s + 64.0f * ((float)len * c + LN64) - 64.0f * c - (float)len * c;
        }
        return;
    }

    // =============== GENERAL PATH (wave 0 only) ===============
    if (tid >= 64) return;
    const int lane = tid;               // class index i, 0..63
    const float INV_C = 1.0f / (float)NCLS;

    int tr8[PD];
    #pragma unroll
    for (int k = 0; k < PD; ++k) tr8[k] = tg[lane + NCLS * k];

    float trow[NCLS];
    #pragma unroll
    for (int q = 0; q < 16; ++q) {
        const float4 v = *reinterpret_cast<const float4*>(&trans[lane * NCLS + q * 4]);
        trow[4*q] = v.x; trow[4*q+1] = v.y; trow[4*q+2] = v.z; trow[4*q+3] = v.w;
    }
    float tmax = -3.0e38f, tsum = 0.f;
    #pragma unroll
    for (int j = 0; j < NCLS; ++j) { tmax = fmaxf(tmax, trow[j]); tsum += trow[j]; }
    float mT = tmax;
    #pragma unroll
    for (int o = 32; o; o >>= 1) mT = fmaxf(mT, __shfl_xor(mT, o));
    h2 tp[NCLS / 2];
    #pragma unroll
    for (int j = 0; j < NCLS; j += 2) {
        const float e0 = __expf(trow[j]     - mT) * 0.015625f;
        const float e1 = __expf(trow[j + 1] - mT) * 0.015625f;
        h2 p; p.x = (_Float16)e0; p.y = (_Float16)e1;
        tp[j >> 1] = p;
    }

    const int   t0 = __shfl(tr8[0], 0);          // tags[0]
    const float rs = __shfl(tsum, t0);           // row-sum of T at row tags[0]
    const float first = lg[t0] + rs;

    float f = 1.0f;
    float B = 0.0f;

    float lgr[PD];
    #pragma unroll
    for (int k = 0; k < PD; ++k) lgr[k] = lg[(size_t)k * NCLS + lane];

    const int nblk = len >> 3;
    const int tail = len & 7;

    #define CRF_STEP(PVAL)                                                     \
    {                                                                          \
        fh_lds[lane] = (_Float16)f;                                            \
        float d0 = 0.f, d1 = 0.f, d2 = 0.f, d3 = 0.f;                          \
        _Pragma("unroll")                                                      \
        for (int j = 0; j < NCLS; j += 16) {                                   \
            const float4 a  = *reinterpret_cast<const float4*>(&fh_lds[j]);    \
            const float4 b4 = *reinterpret_cast<const float4*>(&fh_lds[j+8]);  \
            d0 = FDOT2(tp[(j >> 1) + 0], BC_H2(a.x),  d0);                     \
            d1 = FDOT2(tp[(j >> 1) + 1], BC_H2(a.y),  d1);                     \
            d2 = FDOT2(tp[(j >> 1) + 2], BC_H2(a.z),  d2);                     \
            d3 = FDOT2(tp[(j >> 1) + 3], BC_H2(a.w),  d3);                     \
            d0 = FDOT2(tp[(j >> 1) + 4], BC_H2(b4.x), d0);                     \
            d1 = FDOT2(tp[(j >> 1) + 5], BC_H2(b4.y), d1);                     \
            d2 = FDOT2(tp[(j >> 1) + 6], BC_H2(b4.z), d2);                     \
            d3 = FDOT2(tp[(j >> 1) + 7], BC_H2(b4.w), d3);                     \
        }                                                                      \
        const float dot = (d0 + d1) + (d2 + d3);                               \
        f = dot * (PVAL);                                                      \
    }

    int t = 0;
    for (int b = 0; b < nblk; ++b) {
        #pragma unroll
        for (int k = 0; k < PD; ++k) {
            const float p = __expf(lgr[k] * INV_C);      // off critical path
            int nidx = t + k + PD; nidx = (nidx > TDIM - 1) ? (TDIM - 1) : nidx;
            lgr[k] = lg[(size_t)nidx * NCLS + lane];     // lands 8 steps out
            CRF_STEP(p);
        }
        t += PD;
        if ((b & 7) == 7) {            // periodic renorm
            float r = __builtin_bit_cast(float,
                          __builtin_amdgcn_readfirstlane(__builtin_bit_cast(int, f)));
            r = fmaxf(r, 1e-30f);
            f *= __builtin_amdgcn_rcpf(r);
            B += __logf(r);
        }
    }

    #pragma unroll
    for (int k = 0; k < PD - 1; ++k) {
        if (k < tail) {
            const float p = __expf(lgr[k] * INV_C);
            CRF_STEP(p);
        }
    }
    #undef CRF_STEP

    float g = 0.f;
    #pragma unroll
    for (int k = 0; k < PD; ++k) {
        const int m = 1 + lane + NCLS * k;
        if (m <= len) {
            const int rot  = __shfl(tr8[k], (lane + 1) & 63);        // tg[m], lane<63
            const int wrap = __shfl(tr8[(k + 1) & (PD - 1)], 0);     // tg[m], lane==63
            const int tm = (lane == 63) ? wrap : rot;
            const int tp_ = tr8[k];                                   // tg[m-1]
            g += trans[tm * NCLS + tp_] + lg[(size_t)m * NCLS + tm];
        }
    }

    float v = __logf(f) - g;
    #pragma unroll
    for (int o = 32; o; o >>= 1) v += __shfl_xor(v, o);

    if (lane == 0) {
        const float Bt = (float)len * (mT + LN64) + B;
        out[n] = 64.0f * Bt + v - first;
    }
}

extern "C" void kernel_launch(void* const* d_in, const int* in_sizes, int n_in,
                              void* d_out, int out_size, void* d_ws, size_t ws_size,
                              hipStream_t stream) {
    const float* logits  = (const float*)d_in[0];
    const int*   lengths = (const int*)  d_in[1];
    const int*   tags    = (const int*)  d_in[2];
    const float* trans   = (const float*)d_in[3];
    float* out = (float*)d_out;
    const int N = in_sizes[1];   // 512

    crf_kernel<<<N, 512, 0, stream>>>(logits, lengths, tags, trans, out, N);
}